// Round 10
// baseline (819.721 us; speedup 1.0000x reference)
//
#include <hip/hip_runtime.h>
#include <math.h>

#define HDIM 128
#define EPSLN 1e-5f

// bf16 helpers: RNE float->bf16, exact bf16->float via bit ops
__device__ __forceinline__ unsigned short f2bf(float f) {
  unsigned int u = __float_as_uint(f);
  u = u + 0x7fffu + ((u >> 16) & 1u);
  return (unsigned short)(u >> 16);
}
__device__ __forceinline__ float bf_lo(unsigned int packed) {  // low bf16 -> f32
  return __uint_as_float(packed << 16);
}
__device__ __forceinline__ float bf_hi(unsigned int packed) {  // high bf16 -> f32
  return __uint_as_float(packed & 0xffff0000u);
}

// ---------------- graph preprocessing ----------------

// 4 edges/thread, int4 loads.  atomicAdd result unused -> fire-and-forget.
__global__ __launch_bounds__(256) void count_k(const int* __restrict__ dst,
                                               int* __restrict__ counts, int E_) {
  int base = (blockIdx.x * 256 + threadIdx.x) * 4;
  if (base + 3 < E_) {
    int4 d = *(const int4*)(dst + base);
    atomicAdd(&counts[d.x], 1);
    atomicAdd(&counts[d.y], 1);
    atomicAdd(&counts[d.z], 1);
    atomicAdd(&counts[d.w], 1);
  } else {
    for (int e = base; e < E_; e++) atomicAdd(&counts[dst[e]], 1);
  }
}

__global__ __launch_bounds__(256) void dinv_k(const int* __restrict__ counts,
                                              float* __restrict__ dinv, int n) {
  int i = blockIdx.x * 256 + threadIdx.x;
  if (i < n) dinv[i] = rsqrtf((float)(counts[i] + 1));  // +1 = self loop
}

// scan over counts -> exclusive rowptr.  CHUNK = 1024 elems per block (256 thr x 4)
__global__ __launch_bounds__(256) void scan1_k(const int* __restrict__ counts,
                                               int* __restrict__ bsum, int n) {
  __shared__ int sm[256];
  int t = threadIdx.x;
  int base = blockIdx.x * 1024;
  int s = 0;
  for (int i = 0; i < 4; i++) {
    int idx = base + t * 4 + i;
    if (idx < n) s += counts[idx];
  }
  sm[t] = s;
  __syncthreads();
  for (int off = 128; off; off >>= 1) {
    if (t < off) sm[t] += sm[t + off];
    __syncthreads();
  }
  if (t == 0) bsum[blockIdx.x] = sm[0];
}

__global__ __launch_bounds__(256) void scan2_k(int* __restrict__ bsum,
                                               int* __restrict__ rowptr, int G_, int n) {
  __shared__ int sm[256];
  int t = threadIdx.x;
  int orig = (t < G_) ? bsum[t] : 0;
  sm[t] = orig;
  __syncthreads();
  for (int off = 1; off < 256; off <<= 1) {
    int v = (t >= off) ? sm[t - off] : 0;
    __syncthreads();
    sm[t] += v;
    __syncthreads();
  }
  if (t < G_) bsum[t] = sm[t] - orig;  // exclusive prefix per block
  if (t == 0) rowptr[n] = sm[255];     // total = E (zero padded)
}

__global__ __launch_bounds__(256) void scan3_k(const int* __restrict__ counts,
                                               const int* __restrict__ bsum,
                                               int* __restrict__ rowptr,
                                               int* __restrict__ cursor, int n) {
  __shared__ int sm[256];
  int t = threadIdx.x;
  int base = blockIdx.x * 1024;
  int loc[4];
  int s = 0;
  for (int i = 0; i < 4; i++) {
    int idx = base + t * 4 + i;
    loc[i] = (idx < n) ? counts[idx] : 0;
    s += loc[i];
  }
  sm[t] = s;
  __syncthreads();
  int orig = s;
  for (int off = 1; off < 256; off <<= 1) {
    int v = (t >= off) ? sm[t - off] : 0;
    __syncthreads();
    sm[t] += v;
    __syncthreads();
  }
  int excl = sm[t] - orig + bsum[blockIdx.x];
  for (int i = 0; i < 4; i++) {
    int idx = base + t * 4 + i;
    if (idx < n) {
      rowptr[idx] = excl;
      cursor[idx] = excl;
      excl += loc[i];
    }
  }
}

// 4 edges/thread: FOUR independent atomic->store chains in flight per lane.
// The single-edge version was latency-bound (one ~900cy atomic round-trip in
// flight per wave -> measured 136us, VALUBusy 0.3%).  4x ILP -> ~4x throughput.
__global__ __launch_bounds__(256) void fill_k(const int* __restrict__ src,
                                              const int* __restrict__ dst,
                                              int* __restrict__ cursor,
                                              int* __restrict__ colx, int E_) {
  int base = (blockIdx.x * 256 + threadIdx.x) * 4;
  if (base + 3 < E_) {
    int4 s = *(const int4*)(src + base);
    int4 d = *(const int4*)(dst + base);
    int slot0 = atomicAdd(&cursor[d.x], 1);
    int slot1 = atomicAdd(&cursor[d.y], 1);
    int slot2 = atomicAdd(&cursor[d.z], 1);
    int slot3 = atomicAdd(&cursor[d.w], 1);
    colx[slot0] = s.x;
    colx[slot1] = s.y;
    colx[slot2] = s.z;
    colx[slot3] = s.w;
  } else {
    for (int e = base; e < E_; e++) {
      int slot = atomicAdd(&cursor[dst[e]], 1);
      colx[slot] = src[e];
    }
  }
}

// ---------------- dense GEMM: T'[n x 128](bf16) = dinv ⊙ (A[n x 128] @ W[128 x 128]) --
// block = 256 threads, 64 rows per block.  A tile staged in LDS (32 KB), W via L1/L2.
// Epilogue converts to bf16 (RNE) -> halves the downstream gather bytes.
__global__ __launch_bounds__(256) void gemm_k(const float* __restrict__ A,
                                              const float* __restrict__ W,
                                              const float* __restrict__ dinv,
                                              unsigned short* __restrict__ Out, int n) {
  __shared__ float hs[64 * HDIM];
  int t = threadIdx.x;
  int rowbase = blockIdx.x * 64;
  const float4* A4 = (const float4*)(A + (size_t)rowbase * HDIM);
  for (int i = 0; i < 8; i++) {
    int fi = t + i * 256;              // float4 index within tile (32 per row)
    int row = rowbase + (fi >> 5);
    float4 v = make_float4(0.f, 0.f, 0.f, 0.f);
    if (row < n) v = A4[fi];
    ((float4*)hs)[fi] = v;
  }
  __syncthreads();

  int tc = t & 31;        // col group: cols 4*tc .. 4*tc+3
  int tr = t >> 5;        // row group: rows tr*8 .. tr*8+7
  float acc[8][4];
  for (int i = 0; i < 8; i++)
    for (int j = 0; j < 4; j++) acc[i][j] = 0.f;

  const float4* W4 = (const float4*)W;
  for (int k = 0; k < HDIM; k += 4) {
    float4 w0 = W4[(k + 0) * 32 + tc];
    float4 w1 = W4[(k + 1) * 32 + tc];
    float4 w2 = W4[(k + 2) * 32 + tc];
    float4 w3 = W4[(k + 3) * 32 + tc];
    for (int i = 0; i < 8; i++) {
      float4 h4 = *((const float4*)&hs[(tr * 8 + i) * HDIM + k]);
      acc[i][0] += h4.x * w0.x + h4.y * w1.x + h4.z * w2.x + h4.w * w3.x;
      acc[i][1] += h4.x * w0.y + h4.y * w1.y + h4.z * w2.y + h4.w * w3.y;
      acc[i][2] += h4.x * w0.z + h4.y * w1.z + h4.z * w2.z + h4.w * w3.z;
      acc[i][3] += h4.x * w0.w + h4.y * w1.w + h4.z * w2.w + h4.w * w3.w;
    }
  }
  for (int i = 0; i < 8; i++) {
    int row = rowbase + tr * 8 + i;
    if (row < n) {
      float dv = dinv[row];
      ushort4 o;
      o.x = f2bf(acc[i][0] * dv);
      o.y = f2bf(acc[i][1] * dv);
      o.z = f2bf(acc[i][2] * dv);
      o.w = f2bf(acc[i][3] * dv);
      ((ushort4*)(Out + (size_t)row * HDIM))[tc] = o;
    }
  }
}

// ---------------- aggregation: one wave per dst node (bf16 T', fp32 accumulate) -------
// T' = dinv ⊙ (A·W) in bf16.  out = dinv[d]*(T'[d] + Σ T'[src]) + b.
// Lane holds cols {2*lane, 2*lane+1} as one packed uint (4B/lane, 256B/row).
// Indices for the NEXT pair are prefetched one iteration ahead.
// MODE 0: + bias, relu, layernorm(g,b).   MODE 1: + bias only (emb output).
template <int MODE>
__global__ __launch_bounds__(256) void agg_k(const unsigned short* __restrict__ T,
                                             const int* __restrict__ rowptr,
                                             const int* __restrict__ colx,
                                             const float* __restrict__ dinv,
                                             const float* __restrict__ bias,
                                             const float* __restrict__ lng,
                                             const float* __restrict__ lnb,
                                             float* __restrict__ Out, int n) {
  int wid = (blockIdx.x * 256 + threadIdx.x) >> 6;
  int lane = threadIdx.x & 63;
  if (wid >= n) return;
  int i = wid;
  float di = dinv[i];
  const unsigned int* T32 = (const unsigned int*)T;  // 64 packed uints per row
  // self term
  unsigned int us = T32[(size_t)i * 64 + lane];
  float a0x = bf_lo(us), a0y = bf_hi(us);
  float a1x = 0.f, a1y = 0.f;
  int beg = rowptr[i], end = rowptr[i + 1];
  int e = beg;
  int c0 = 0, c1 = 0;
  if (e < end) c0 = colx[e];
  if (e + 1 < end) c1 = colx[e + 1];
  for (; e + 1 < end; e += 2) {
    unsigned int u0 = T32[(size_t)c0 * 64 + lane];
    unsigned int u1 = T32[(size_t)c1 * 64 + lane];
    // prefetch next pair's indices before consuming the gathers
    if (e + 2 < end) c0 = colx[e + 2];
    if (e + 3 < end) c1 = colx[e + 3];
    a0x += bf_lo(u0); a0y += bf_hi(u0);
    a1x += bf_lo(u1); a1y += bf_hi(u1);
  }
  if (e < end) {  // odd tail (c0 holds the right index by construction)
    unsigned int u0 = T32[(size_t)c0 * 64 + lane];
    a0x += bf_lo(u0); a0y += bf_hi(u0);
  }
  float2 bb = ((const float2*)bias)[lane];
  float2 acc;
  acc.x = (a0x + a1x) * di + bb.x;
  acc.y = (a0y + a1y) * di + bb.y;
  if (MODE == 0) {
    acc.x = fmaxf(acc.x, 0.f);
    acc.y = fmaxf(acc.y, 0.f);
    float s1 = acc.x + acc.y;
    float s2 = acc.x * acc.x + acc.y * acc.y;
    for (int off = 1; off < 64; off <<= 1) {
      s1 += __shfl_xor(s1, off);
      s2 += __shfl_xor(s2, off);
    }
    float mu = s1 * (1.f / 128.f);
    float var = s2 * (1.f / 128.f) - mu * mu;
    float r = rsqrtf(var + EPSLN);
    float2 gg = ((const float2*)lng)[lane];
    float2 b2 = ((const float2*)lnb)[lane];
    acc.x = (acc.x - mu) * r * gg.x + b2.x;
    acc.y = (acc.y - mu) * r * gg.y + b2.y;
  }
  ((float2*)(Out + (size_t)i * HDIM))[lane] = acc;
}

// ---------------- fused head: relu -> Linear(128) -> Linear(2) -> log_softmax ----------------
// Same register-blocked GEMM structure as gemm_k (W1 read once per BLOCK, not per node).
__global__ __launch_bounds__(256) void head_k(const float* __restrict__ emb,
                                              const float* __restrict__ W1_,
                                              const float* __restrict__ b1_,
                                              const float* __restrict__ W2_,
                                              const float* __restrict__ b2_,
                                              float* __restrict__ outp, int n) {
  __shared__ float hs[64 * HDIM];
  int t = threadIdx.x;
  int rowbase = blockIdx.x * 64;
  const float4* A4 = (const float4*)(emb + (size_t)rowbase * HDIM);
  for (int i = 0; i < 8; i++) {
    int fi = t + i * 256;
    int row = rowbase + (fi >> 5);
    float4 v = make_float4(0.f, 0.f, 0.f, 0.f);
    if (row < n) v = A4[fi];
    v.x = fmaxf(v.x, 0.f);  // relu while staging
    v.y = fmaxf(v.y, 0.f);
    v.z = fmaxf(v.z, 0.f);
    v.w = fmaxf(v.w, 0.f);
    ((float4*)hs)[fi] = v;
  }
  __syncthreads();

  int tc = t & 31;
  int tr = t >> 5;
  float acc[8][4];
  float4 binit = ((const float4*)b1_)[tc];
  for (int i = 0; i < 8; i++) {
    acc[i][0] = binit.x; acc[i][1] = binit.y; acc[i][2] = binit.z; acc[i][3] = binit.w;
  }

  const float4* W4 = (const float4*)W1_;
  for (int k = 0; k < HDIM; k += 4) {
    float4 w0 = W4[(k + 0) * 32 + tc];
    float4 w1 = W4[(k + 1) * 32 + tc];
    float4 w2 = W4[(k + 2) * 32 + tc];
    float4 w3 = W4[(k + 3) * 32 + tc];
    for (int i = 0; i < 8; i++) {
      float4 h4 = *((const float4*)&hs[(tr * 8 + i) * HDIM + k]);
      acc[i][0] += h4.x * w0.x + h4.y * w1.x + h4.z * w2.x + h4.w * w3.x;
      acc[i][1] += h4.x * w0.y + h4.y * w1.y + h4.z * w2.y + h4.w * w3.y;
      acc[i][2] += h4.x * w0.z + h4.y * w1.z + h4.z * w2.z + h4.w * w3.z;
      acc[i][3] += h4.x * w0.w + h4.y * w1.w + h4.z * w2.w + h4.w * w3.w;
    }
  }

  // second linear: z row dotted with W2 [128 x 2].  This thread owns cols 4*tc..4*tc+3.
  float2 w2c[4];
  for (int j = 0; j < 4; j++) w2c[j] = ((const float2*)W2_)[4 * tc + j];
  float o0[8], o1[8];
  for (int i = 0; i < 8; i++) {
    o0[i] = acc[i][0] * w2c[0].x + acc[i][1] * w2c[1].x + acc[i][2] * w2c[2].x + acc[i][3] * w2c[3].x;
    o1[i] = acc[i][0] * w2c[0].y + acc[i][1] * w2c[1].y + acc[i][2] * w2c[2].y + acc[i][3] * w2c[3].y;
  }
  // reduce across the 32 lanes sharing this tr (xor offsets < 32 stay within the half-wave)
  for (int off = 1; off < 32; off <<= 1) {
    for (int i = 0; i < 8; i++) {
      o0[i] += __shfl_xor(o0[i], off);
      o1[i] += __shfl_xor(o1[i], off);
    }
  }
  if (tc == 0) {
    float B0 = b2_[0], B1 = b2_[1];
    for (int i = 0; i < 8; i++) {
      int row = rowbase + tr * 8 + i;
      if (row < n) {
        float a = o0[i] + B0, b = o1[i] + B1;
        float m = fmaxf(a, b);
        float lse = m + logf(expf(a - m) + expf(b - m));
        outp[(size_t)row * 2 + 0] = a - lse;
        outp[(size_t)row * 2 + 1] = b - lse;
      }
    }
  }
}

// ---------------- launcher ----------------

extern "C" void kernel_launch(void* const* d_in, const int* in_sizes, int n_in,
                              void* d_out, int out_size, void* d_ws, size_t ws_size,
                              hipStream_t stream) {
  const float* x = (const float*)d_in[0];
  const int* ei = (const int*)d_in[1];
  const float* W1 = (const float*)d_in[2];
  const float* b1 = (const float*)d_in[3];
  const float* W2 = (const float*)d_in[4];
  const float* b2 = (const float*)d_in[5];
  const float* W3 = (const float*)d_in[6];
  const float* b3 = (const float*)d_in[7];
  const float* ln1g = (const float*)d_in[8];
  const float* ln1b = (const float*)d_in[9];
  const float* ln2g = (const float*)d_in[10];
  const float* ln2b = (const float*)d_in[11];
  const float* mpW1 = (const float*)d_in[12];
  const float* mpb1 = (const float*)d_in[13];
  const float* mpW2 = (const float*)d_in[14];
  const float* mpb2 = (const float*)d_in[15];

  const int N = in_sizes[0] / HDIM;
  const int E = in_sizes[1] / 2;
  const int* srcp = ei;
  const int* dstp = ei + E;

  // carve workspace
  char* p = (char*)d_ws;
  auto carve = [&](size_t bytes) {
    void* r = (void*)p;
    p += (bytes + 255) & ~(size_t)255;
    return r;
  };
  int* counts = (int*)carve((size_t)N * 4);
  int* rowptr = (int*)carve((size_t)(N + 1) * 4);
  int* cursor = (int*)carve((size_t)N * 4);
  int* bsum = (int*)carve(256 * 4);
  float* dinv = (float*)carve((size_t)N * 4);
  int* colx = (int*)carve((size_t)E * 4);
  unsigned short* bufT = (unsigned short*)carve((size_t)N * HDIM * 2);  // bf16 T'
  float* bufAct = (float*)carve((size_t)N * HDIM * 4);                  // fp32 activations

  float* emb = (float*)d_out;                    // N x 128
  float* logits = (float*)d_out + (size_t)N * HDIM;  // N x 2

  const int G = (N + 1023) / 1024;  // scan blocks (<= 256)
  const int E4 = (E + 3) / 4;       // 4 edges per thread

  hipMemsetAsync(counts, 0, (size_t)N * 4, stream);
  count_k<<<(E4 + 255) / 256, 256, 0, stream>>>(dstp, counts, E);
  dinv_k<<<(N + 255) / 256, 256, 0, stream>>>(counts, dinv, N);
  scan1_k<<<G, 256, 0, stream>>>(counts, bsum, N);
  scan2_k<<<1, 256, 0, stream>>>(bsum, rowptr, G, N);
  scan3_k<<<G, 256, 0, stream>>>(counts, bsum, rowptr, cursor, N);
  fill_k<<<(E4 + 255) / 256, 256, 0, stream>>>(srcp, dstp, cursor, colx, E);

  const int gemmG = (N + 63) / 64;
  const int aggG = (N * 64 + 255) / 256;

  // layer 1: x -> bufT (bf16, pre-scaled) -> (agg+relu+LN) bufAct
  gemm_k<<<gemmG, 256, 0, stream>>>(x, W1, dinv, bufT, N);
  agg_k<0><<<aggG, 256, 0, stream>>>(bufT, rowptr, colx, dinv, b1, ln1g, ln1b, bufAct, N);
  // layer 2
  gemm_k<<<gemmG, 256, 0, stream>>>(bufAct, W2, dinv, bufT, N);
  agg_k<0><<<aggG, 256, 0, stream>>>(bufT, rowptr, colx, dinv, b2, ln2g, ln2b, bufAct, N);
  // layer 3 -> emb (pre-relu) straight into d_out
  gemm_k<<<gemmG, 256, 0, stream>>>(bufAct, W3, dinv, bufT, N);
  agg_k<1><<<aggG, 256, 0, stream>>>(bufT, rowptr, colx, dinv, b3, nullptr, nullptr, emb, N);
  // head (register-blocked, fused log-softmax)
  head_k<<<gemmG, 256, 0, stream>>>(emb, mpW1, mpb1, mpW2, mpb2, logits, N);
}

// Round 13
// 688.993 us; speedup vs baseline: 1.1897x; 1.1897x over previous
//
#include <hip/hip_runtime.h>
#include <math.h>

#define HDIM 128
#define EPSLN 1e-5f
#define BSH 8         // bucket shift: 256 nodes per bucket
#define CHUNK 8192    // edges per block in histA/scatA
#define EPB 32        // CHUNK/256
#define CAPB 8192     // LDS staging capacity (edges) per bucket in passB

// bf16 helpers: RNE float->bf16, exact bf16->float via bit ops
__device__ __forceinline__ unsigned short f2bf(float f) {
  unsigned int u = __float_as_uint(f);
  u = u + 0x7fffu + ((u >> 16) & 1u);
  return (unsigned short)(u >> 16);
}
__device__ __forceinline__ float bf_lo(unsigned int packed) {
  return __uint_as_float(packed << 16);
}
__device__ __forceinline__ float bf_hi(unsigned int packed) {
  return __uint_as_float(packed & 0xffff0000u);
}

// ---------------- CSR build via bucket partition (no scattered 4B writes) ----------

// per-bucket histogram
__global__ __launch_bounds__(256) void histA_k(const int* __restrict__ dst,
                                               int* __restrict__ bsize, int E_) {
  __shared__ int h[512];
  int t = threadIdx.x;
  h[t] = 0; h[t + 256] = 0;
  __syncthreads();
  int base = blockIdx.x * CHUNK;
  for (int i = 0; i < EPB; i++) {
    int idx = base + i * 256 + t;
    if (idx < E_) atomicAdd(&h[dst[idx] >> BSH], 1);
  }
  __syncthreads();
  int v = h[t];       if (v) atomicAdd(&bsize[t], v);
  v = h[t + 256];     if (v) atomicAdd(&bsize[t + 256], v);
}

// exclusive scan of bucket sizes (NB <= 512) -> bbase, bcur; also rowptr[n]=E
__global__ __launch_bounds__(256) void scanA_k(const int* __restrict__ bsize,
                                               int* __restrict__ bbase,
                                               int* __restrict__ bcur,
                                               int* __restrict__ rowptr,
                                               int NB, int n, int E_) {
  __shared__ int sm[512];
  int t = threadIdx.x;
  sm[t] = (t < NB) ? bsize[t] : 0;
  sm[t + 256] = (t + 256 < NB) ? bsize[t + 256] : 0;
  __syncthreads();
  for (int off = 1; off < 512; off <<= 1) {
    int v0 = (t >= off) ? sm[t - off] : 0;
    int v1 = (t + 256 >= off) ? sm[t + 256 - off] : 0;
    __syncthreads();
    sm[t] += v0;
    sm[t + 256] += v1;
    __syncthreads();
  }
  if (t < NB) { int ex = (t == 0) ? 0 : sm[t - 1]; bbase[t] = ex; bcur[t] = ex; }
  int u = t + 256;
  if (u < NB) { int ex = sm[u - 1]; bbase[u] = ex; bcur[u] = ex; }
  if (t == 0) { bbase[NB] = sm[NB - 1]; rowptr[n] = E_; }
}

// partition edges into bucket-contiguous binned[] (writes land in ~20-edge runs)
__global__ __launch_bounds__(256) void scatA_k(const int* __restrict__ src,
                                               const int* __restrict__ dst,
                                               int* __restrict__ bcur,
                                               uint2* __restrict__ binned, int E_) {
  __shared__ int h[512];
  __shared__ int cur[512];
  int t = threadIdx.x;
  h[t] = 0; h[t + 256] = 0;
  __syncthreads();
  int base = blockIdx.x * CHUNK;
  for (int i = 0; i < EPB; i++) {
    int idx = base + i * 256 + t;
    if (idx < E_) atomicAdd(&h[dst[idx] >> BSH], 1);
  }
  __syncthreads();
  int v = h[t];       cur[t] = v ? atomicAdd(&bcur[t], v) : 0;
  v = h[t + 256];     cur[t + 256] = v ? atomicAdd(&bcur[t + 256], v) : 0;
  __syncthreads();
  for (int i = 0; i < EPB; i++) {
    int idx = base + i * 256 + t;
    if (idx < E_) {
      int d = dst[idx];
      int slot = atomicAdd(&cur[d >> BSH], 1);
      binned[slot] = make_uint2((unsigned)src[idx], (unsigned)d);
    }
  }
}

// per bucket: local count/scan -> rowptr + dinv; colx segment built in LDS, streamed out
__global__ __launch_bounds__(256) void passB_k(const uint2* __restrict__ binned,
                                               const int* __restrict__ bbase,
                                               int* __restrict__ rowptr,
                                               float* __restrict__ dinv,
                                               int* __restrict__ colx, int n) {
  __shared__ int cnt[256];
  __shared__ int cur[256];
  __shared__ int stage[CAPB];
  int b = blockIdx.x;
  int t = threadIdx.x;
  int beg = bbase[b], end = bbase[b + 1];
  int sz = end - beg;
  int nb0 = b << BSH;
  cnt[t] = 0;
  __syncthreads();
  for (int i = t; i < sz; i += 256) {
    uint2 e = binned[beg + i];
    atomicAdd(&cnt[e.y & 255], 1);
  }
  __syncthreads();
  int myc = cnt[t];
  cur[t] = myc;
  __syncthreads();
  for (int off = 1; off < 256; off <<= 1) {
    int v = (t >= off) ? cur[t - off] : 0;
    __syncthreads();
    cur[t] += v;
    __syncthreads();
  }
  int excl = cur[t] - myc;
  int node = nb0 + t;
  if (node < n) {
    rowptr[node] = beg + excl;
    dinv[node] = rsqrtf((float)(myc + 1));  // +1 = self loop
  }
  __syncthreads();
  cur[t] = excl;
  __syncthreads();
  if (sz <= CAPB) {
    for (int i = t; i < sz; i += 256) {
      uint2 e = binned[beg + i];
      int slot = atomicAdd(&cur[e.y & 255], 1);
      stage[slot] = (int)e.x;
    }
    __syncthreads();
    for (int i = t; i < sz; i += 256) colx[beg + i] = stage[i];
  } else {  // overflow fallback (never triggers for this input)
    for (int i = t; i < sz; i += 256) {
      uint2 e = binned[beg + i];
      int slot = atomicAdd(&cur[e.y & 255], 1);
      colx[beg + slot] = (int)e.x;
    }
  }
}

// ---------------- dense GEMM: T'[n x 128](bf16) = dinv ⊙ (A[n x 128] @ W[128 x 128]) --
__global__ __launch_bounds__(256) void gemm_k(const float* __restrict__ A,
                                              const float* __restrict__ W,
                                              const float* __restrict__ dinv,
                                              unsigned short* __restrict__ Out, int n) {
  __shared__ float hs[64 * HDIM];
  int t = threadIdx.x;
  int rowbase = blockIdx.x * 64;
  const float4* A4 = (const float4*)(A + (size_t)rowbase * HDIM);
  for (int i = 0; i < 8; i++) {
    int fi = t + i * 256;
    int row = rowbase + (fi >> 5);
    float4 v = make_float4(0.f, 0.f, 0.f, 0.f);
    if (row < n) v = A4[fi];
    ((float4*)hs)[fi] = v;
  }
  __syncthreads();

  int tc = t & 31;
  int tr = t >> 5;
  float acc[8][4];
  for (int i = 0; i < 8; i++)
    for (int j = 0; j < 4; j++) acc[i][j] = 0.f;

  const float4* W4 = (const float4*)W;
  for (int k = 0; k < HDIM; k += 4) {
    float4 w0 = W4[(k + 0) * 32 + tc];
    float4 w1 = W4[(k + 1) * 32 + tc];
    float4 w2 = W4[(k + 2) * 32 + tc];
    float4 w3 = W4[(k + 3) * 32 + tc];
    for (int i = 0; i < 8; i++) {
      float4 h4 = *((const float4*)&hs[(tr * 8 + i) * HDIM + k]);
      acc[i][0] += h4.x * w0.x + h4.y * w1.x + h4.z * w2.x + h4.w * w3.x;
      acc[i][1] += h4.x * w0.y + h4.y * w1.y + h4.z * w2.y + h4.w * w3.y;
      acc[i][2] += h4.x * w0.z + h4.y * w1.z + h4.z * w2.z + h4.w * w3.z;
      acc[i][3] += h4.x * w0.w + h4.y * w1.w + h4.z * w2.w + h4.w * w3.w;
    }
  }
  for (int i = 0; i < 8; i++) {
    int row = rowbase + tr * 8 + i;
    if (row < n) {
      float dv = dinv[row];
      ushort4 o;
      o.x = f2bf(acc[i][0] * dv);
      o.y = f2bf(acc[i][1] * dv);
      o.z = f2bf(acc[i][2] * dv);
      o.w = f2bf(acc[i][3] * dv);
      ((ushort4*)(Out + (size_t)row * HDIM))[tc] = o;
    }
  }
}

// ---------------- aggregation: one wave per dst node (bf16 T', fp32 accumulate) -------
template <int MODE>
__global__ __launch_bounds__(256) void agg_k(const unsigned short* __restrict__ T,
                                             const int* __restrict__ rowptr,
                                             const int* __restrict__ colx,
                                             const float* __restrict__ dinv,
                                             const float* __restrict__ bias,
                                             const float* __restrict__ lng,
                                             const float* __restrict__ lnb,
                                             float* __restrict__ Out, int n) {
  int wid = (blockIdx.x * 256 + threadIdx.x) >> 6;
  int lane = threadIdx.x & 63;
  if (wid >= n) return;
  int i = wid;
  float di = dinv[i];
  const unsigned int* T32 = (const unsigned int*)T;
  unsigned int us = T32[(size_t)i * 64 + lane];
  float a0x = bf_lo(us), a0y = bf_hi(us);
  float a1x = 0.f, a1y = 0.f;
  int beg = rowptr[i], end = rowptr[i + 1];
  int e = beg;
  int c0 = 0, c1 = 0;
  if (e < end) c0 = colx[e];
  if (e + 1 < end) c1 = colx[e + 1];
  for (; e + 1 < end; e += 2) {
    unsigned int u0 = T32[(size_t)c0 * 64 + lane];
    unsigned int u1 = T32[(size_t)c1 * 64 + lane];
    if (e + 2 < end) c0 = colx[e + 2];
    if (e + 3 < end) c1 = colx[e + 3];
    a0x += bf_lo(u0); a0y += bf_hi(u0);
    a1x += bf_lo(u1); a1y += bf_hi(u1);
  }
  if (e < end) {
    unsigned int u0 = T32[(size_t)c0 * 64 + lane];
    a0x += bf_lo(u0); a0y += bf_hi(u0);
  }
  float2 bb = ((const float2*)bias)[lane];
  float2 acc;
  acc.x = (a0x + a1x) * di + bb.x;
  acc.y = (a0y + a1y) * di + bb.y;
  if (MODE == 0) {
    acc.x = fmaxf(acc.x, 0.f);
    acc.y = fmaxf(acc.y, 0.f);
    float s1 = acc.x + acc.y;
    float s2 = acc.x * acc.x + acc.y * acc.y;
    for (int off = 1; off < 64; off <<= 1) {
      s1 += __shfl_xor(s1, off);
      s2 += __shfl_xor(s2, off);
    }
    float mu = s1 * (1.f / 128.f);
    float var = s2 * (1.f / 128.f) - mu * mu;
    float r = rsqrtf(var + EPSLN);
    float2 gg = ((const float2*)lng)[lane];
    float2 b2 = ((const float2*)lnb)[lane];
    acc.x = (acc.x - mu) * r * gg.x + b2.x;
    acc.y = (acc.y - mu) * r * gg.y + b2.y;
  }
  ((float2*)(Out + (size_t)i * HDIM))[lane] = acc;
}

// ---------------- fused head: relu -> Linear(128) -> Linear(2) -> log_softmax ---------
__global__ __launch_bounds__(256) void head_k(const float* __restrict__ emb,
                                              const float* __restrict__ W1_,
                                              const float* __restrict__ b1_,
                                              const float* __restrict__ W2_,
                                              const float* __restrict__ b2_,
                                              float* __restrict__ outp, int n) {
  __shared__ float hs[64 * HDIM];
  int t = threadIdx.x;
  int rowbase = blockIdx.x * 64;
  const float4* A4 = (const float4*)(emb + (size_t)rowbase * HDIM);
  for (int i = 0; i < 8; i++) {
    int fi = t + i * 256;
    int row = rowbase + (fi >> 5);
    float4 v = make_float4(0.f, 0.f, 0.f, 0.f);
    if (row < n) v = A4[fi];
    v.x = fmaxf(v.x, 0.f);
    v.y = fmaxf(v.y, 0.f);
    v.z = fmaxf(v.z, 0.f);
    v.w = fmaxf(v.w, 0.f);
    ((float4*)hs)[fi] = v;
  }
  __syncthreads();

  int tc = t & 31;
  int tr = t >> 5;
  float acc[8][4];
  float4 binit = ((const float4*)b1_)[tc];
  for (int i = 0; i < 8; i++) {
    acc[i][0] = binit.x; acc[i][1] = binit.y; acc[i][2] = binit.z; acc[i][3] = binit.w;
  }

  const float4* W4 = (const float4*)W1_;
  for (int k = 0; k < HDIM; k += 4) {
    float4 w0 = W4[(k + 0) * 32 + tc];
    float4 w1 = W4[(k + 1) * 32 + tc];
    float4 w2 = W4[(k + 2) * 32 + tc];
    float4 w3 = W4[(k + 3) * 32 + tc];
    for (int i = 0; i < 8; i++) {
      float4 h4 = *((const float4*)&hs[(tr * 8 + i) * HDIM + k]);
      acc[i][0] += h4.x * w0.x + h4.y * w1.x + h4.z * w2.x + h4.w * w3.x;
      acc[i][1] += h4.x * w0.y + h4.y * w1.y + h4.z * w2.y + h4.w * w3.y;
      acc[i][2] += h4.x * w0.z + h4.y * w1.z + h4.z * w2.z + h4.w * w3.z;
      acc[i][3] += h4.x * w0.w + h4.y * w1.w + h4.z * w2.w + h4.w * w3.w;
    }
  }

  float2 w2c[4];
  for (int j = 0; j < 4; j++) w2c[j] = ((const float2*)W2_)[4 * tc + j];
  float o0[8], o1[8];
  for (int i = 0; i < 8; i++) {
    o0[i] = acc[i][0] * w2c[0].x + acc[i][1] * w2c[1].x + acc[i][2] * w2c[2].x + acc[i][3] * w2c[3].x;
    o1[i] = acc[i][0] * w2c[0].y + acc[i][1] * w2c[1].y + acc[i][2] * w2c[2].y + acc[i][3] * w2c[3].y;
  }
  for (int off = 1; off < 32; off <<= 1) {
    for (int i = 0; i < 8; i++) {
      o0[i] += __shfl_xor(o0[i], off);
      o1[i] += __shfl_xor(o1[i], off);
    }
  }
  if (tc == 0) {
    float B0 = b2_[0], B1 = b2_[1];
    for (int i = 0; i < 8; i++) {
      int row = rowbase + tr * 8 + i;
      if (row < n) {
        float a = o0[i] + B0, b = o1[i] + B1;
        float m = fmaxf(a, b);
        float lse = m + logf(expf(a - m) + expf(b - m));
        outp[(size_t)row * 2 + 0] = a - lse;
        outp[(size_t)row * 2 + 1] = b - lse;
      }
    }
  }
}

// ---------------- launcher ----------------

extern "C" void kernel_launch(void* const* d_in, const int* in_sizes, int n_in,
                              void* d_out, int out_size, void* d_ws, size_t ws_size,
                              hipStream_t stream) {
  const float* x = (const float*)d_in[0];
  const int* ei = (const int*)d_in[1];
  const float* W1 = (const float*)d_in[2];
  const float* b1 = (const float*)d_in[3];
  const float* W2 = (const float*)d_in[4];
  const float* b2 = (const float*)d_in[5];
  const float* W3 = (const float*)d_in[6];
  const float* b3 = (const float*)d_in[7];
  const float* ln1g = (const float*)d_in[8];
  const float* ln1b = (const float*)d_in[9];
  const float* ln2g = (const float*)d_in[10];
  const float* ln2b = (const float*)d_in[11];
  const float* mpW1 = (const float*)d_in[12];
  const float* mpb1 = (const float*)d_in[13];
  const float* mpW2 = (const float*)d_in[14];
  const float* mpb2 = (const float*)d_in[15];

  const int N = in_sizes[0] / HDIM;
  const int E = in_sizes[1] / 2;
  const int* srcp = ei;
  const int* dstp = ei + E;
  const int NB = (N + 255) >> BSH;   // buckets of 256 nodes (<= 512)

  // carve workspace
  char* p = (char*)d_ws;
  auto carve = [&](size_t bytes) {
    void* r = (void*)p;
    p += (bytes + 255) & ~(size_t)255;
    return r;
  };
  int* bsize = (int*)carve(512 * 4);
  int* bbase = (int*)carve(513 * 4);
  int* bcur = (int*)carve(512 * 4);
  int* rowptr = (int*)carve((size_t)(N + 1) * 4);
  float* dinv = (float*)carve((size_t)N * 4);
  int* colx = (int*)carve((size_t)E * 4);
  uint2* binned = (uint2*)carve((size_t)E * 8);
  unsigned short* bufT = (unsigned short*)carve((size_t)N * HDIM * 2);  // bf16 T'
  float* bufAct = (float*)carve((size_t)N * HDIM * 4);                  // fp32 activations

  float* emb = (float*)d_out;                        // N x 128
  float* logits = (float*)d_out + (size_t)N * HDIM;  // N x 2

  const int chunkG = (E + CHUNK - 1) / CHUNK;

  hipMemsetAsync(bsize, 0, 512 * 4, stream);
  histA_k<<<chunkG, 256, 0, stream>>>(dstp, bsize, E);
  scanA_k<<<1, 256, 0, stream>>>(bsize, bbase, bcur, rowptr, NB, N, E);
  scatA_k<<<chunkG, 256, 0, stream>>>(srcp, dstp, bcur, binned, E);
  passB_k<<<NB, 256, 0, stream>>>(binned, bbase, rowptr, dinv, colx, N);

  const int gemmG = (N + 63) / 64;
  const int aggG = (N * 64 + 255) / 256;

  // layer 1: x -> bufT (bf16, pre-scaled) -> (agg+relu+LN) bufAct
  gemm_k<<<gemmG, 256, 0, stream>>>(x, W1, dinv, bufT, N);
  agg_k<0><<<aggG, 256, 0, stream>>>(bufT, rowptr, colx, dinv, b1, ln1g, ln1b, bufAct, N);
  // layer 2
  gemm_k<<<gemmG, 256, 0, stream>>>(bufAct, W2, dinv, bufT, N);
  agg_k<0><<<aggG, 256, 0, stream>>>(bufT, rowptr, colx, dinv, b2, ln2g, ln2b, bufAct, N);
  // layer 3 -> emb (pre-relu) straight into d_out
  gemm_k<<<gemmG, 256, 0, stream>>>(bufAct, W3, dinv, bufT, N);
  agg_k<1><<<aggG, 256, 0, stream>>>(bufT, rowptr, colx, dinv, b3, nullptr, nullptr, emb, N);
  // head (register-blocked, fused log-softmax)
  head_k<<<gemmG, 256, 0, stream>>>(emb, mpW1, mpb1, mpW2, mpb2, logits, N);
}

// Round 14
// 621.345 us; speedup vs baseline: 1.3193x; 1.1089x over previous
//
#include <hip/hip_runtime.h>
#include <math.h>

#define HDIM 128
#define EPSLN 1e-5f
#define BSH 8         // bucket shift: 256 nodes per bucket
#define CHUNK 8192    // edges per block in histA/scatA
#define EPB 32        // CHUNK/256
#define CAPB 8192     // LDS staging capacity (edges) per bucket in passB
#define LDA 136       // padded LDS row stride in shorts (272 B: 16B-aligned, 2-way banks)

typedef __attribute__((ext_vector_type(8))) short bf16x8;  // 8 bf16 (4 VGPRs)
typedef __attribute__((ext_vector_type(4))) float f32x4;   // MFMA accumulator

// bf16 helpers: RNE float->bf16, exact bf16->float via bit ops
__device__ __forceinline__ unsigned short f2bf(float f) {
  unsigned int u = __float_as_uint(f);
  u = u + 0x7fffu + ((u >> 16) & 1u);
  return (unsigned short)(u >> 16);
}
__device__ __forceinline__ float bf_lo(unsigned int packed) {
  return __uint_as_float(packed << 16);
}
__device__ __forceinline__ float bf_hi(unsigned int packed) {
  return __uint_as_float(packed & 0xffff0000u);
}

// ---------------- CSR build via bucket partition (no scattered 4B writes) ----------

__global__ __launch_bounds__(256) void histA_k(const int* __restrict__ dst,
                                               int* __restrict__ bsize, int E_) {
  __shared__ int h[512];
  int t = threadIdx.x;
  h[t] = 0; h[t + 256] = 0;
  __syncthreads();
  int base = blockIdx.x * CHUNK;
  for (int i = 0; i < EPB; i++) {
    int idx = base + i * 256 + t;
    if (idx < E_) atomicAdd(&h[dst[idx] >> BSH], 1);
  }
  __syncthreads();
  int v = h[t];       if (v) atomicAdd(&bsize[t], v);
  v = h[t + 256];     if (v) atomicAdd(&bsize[t + 256], v);
}

__global__ __launch_bounds__(256) void scanA_k(const int* __restrict__ bsize,
                                               int* __restrict__ bbase,
                                               int* __restrict__ bcur,
                                               int* __restrict__ rowptr,
                                               int NB, int n, int E_) {
  __shared__ int sm[512];
  int t = threadIdx.x;
  sm[t] = (t < NB) ? bsize[t] : 0;
  sm[t + 256] = (t + 256 < NB) ? bsize[t + 256] : 0;
  __syncthreads();
  for (int off = 1; off < 512; off <<= 1) {
    int v0 = (t >= off) ? sm[t - off] : 0;
    int v1 = (t + 256 >= off) ? sm[t + 256 - off] : 0;
    __syncthreads();
    sm[t] += v0;
    sm[t + 256] += v1;
    __syncthreads();
  }
  if (t < NB) { int ex = (t == 0) ? 0 : sm[t - 1]; bbase[t] = ex; bcur[t] = ex; }
  int u = t + 256;
  if (u < NB) { int ex = sm[u - 1]; bbase[u] = ex; bcur[u] = ex; }
  if (t == 0) { bbase[NB] = sm[NB - 1]; rowptr[n] = E_; }
}

__global__ __launch_bounds__(256) void scatA_k(const int* __restrict__ src,
                                               const int* __restrict__ dst,
                                               int* __restrict__ bcur,
                                               uint2* __restrict__ binned, int E_) {
  __shared__ int h[512];
  __shared__ int cur[512];
  int t = threadIdx.x;
  h[t] = 0; h[t + 256] = 0;
  __syncthreads();
  int base = blockIdx.x * CHUNK;
  for (int i = 0; i < EPB; i++) {
    int idx = base + i * 256 + t;
    if (idx < E_) atomicAdd(&h[dst[idx] >> BSH], 1);
  }
  __syncthreads();
  int v = h[t];       cur[t] = v ? atomicAdd(&bcur[t], v) : 0;
  v = h[t + 256];     cur[t + 256] = v ? atomicAdd(&bcur[t + 256], v) : 0;
  __syncthreads();
  for (int i = 0; i < EPB; i++) {
    int idx = base + i * 256 + t;
    if (idx < E_) {
      int d = dst[idx];
      int slot = atomicAdd(&cur[d >> BSH], 1);
      binned[slot] = make_uint2((unsigned)src[idx], (unsigned)d);
    }
  }
}

__global__ __launch_bounds__(256) void passB_k(const uint2* __restrict__ binned,
                                               const int* __restrict__ bbase,
                                               int* __restrict__ rowptr,
                                               float* __restrict__ dinv,
                                               int* __restrict__ colx, int n) {
  __shared__ int cnt[256];
  __shared__ int cur[256];
  __shared__ int stage[CAPB];
  int b = blockIdx.x;
  int t = threadIdx.x;
  int beg = bbase[b], end = bbase[b + 1];
  int sz = end - beg;
  int nb0 = b << BSH;
  cnt[t] = 0;
  __syncthreads();
  for (int i = t; i < sz; i += 256) {
    uint2 e = binned[beg + i];
    atomicAdd(&cnt[e.y & 255], 1);
  }
  __syncthreads();
  int myc = cnt[t];
  cur[t] = myc;
  __syncthreads();
  for (int off = 1; off < 256; off <<= 1) {
    int v = (t >= off) ? cur[t - off] : 0;
    __syncthreads();
    cur[t] += v;
    __syncthreads();
  }
  int excl = cur[t] - myc;
  int node = nb0 + t;
  if (node < n) {
    rowptr[node] = beg + excl;
    dinv[node] = rsqrtf((float)(myc + 1));  // +1 = self loop
  }
  __syncthreads();
  cur[t] = excl;
  __syncthreads();
  if (sz <= CAPB) {
    for (int i = t; i < sz; i += 256) {
      uint2 e = binned[beg + i];
      int slot = atomicAdd(&cur[e.y & 255], 1);
      stage[slot] = (int)e.x;
    }
    __syncthreads();
    for (int i = t; i < sz; i += 256) colx[beg + i] = stage[i];
  } else {
    for (int i = t; i < sz; i += 256) {
      uint2 e = binned[beg + i];
      int slot = atomicAdd(&cur[e.y & 255], 1);
      colx[beg + slot] = (int)e.x;
    }
  }
}

// ---------------- MFMA GEMM: T'[n x 128](bf16) = dinv ⊙ (bf16(A) @ bf16(W)) ----------
// 128-row tile, 4 waves x (2 m-tiles of 16 rows), full 128 cols per wave.
// A-tile and W^T staged in LDS as bf16 with +8-short row pad (2-way banks = free).
// mfma_f32_16x16x32_bf16: A/B frag = 8 bf16 along K per lane (m/n = lane&15,
// k = (lane>>4)*8+j); D: col = lane&15, row = (lane>>4)*4 + reg  [guide m89/m91].
__global__ __launch_bounds__(256) void gemm_k(const float* __restrict__ A,
                                              const float* __restrict__ W,
                                              const float* __restrict__ dinv,
                                              unsigned short* __restrict__ Out, int n) {
  __shared__ short As[128 * LDA];
  __shared__ short Ws[128 * LDA];
  int t = threadIdx.x;
  int rowbase = blockIdx.x * 128;

  // stage W transposed: Ws[c][k] = bf16(W[k][c]); global reads coalesced
  #pragma unroll
  for (int i = 0; i < 64; i++) {
    int idx = t + i * 256;            // 0..16383
    int k = idx >> 7, c = idx & 127;
    Ws[c * LDA + k] = (short)f2bf(W[idx]);
  }
  // stage A tile: As[r][c] = bf16(A[rowbase+r][c]); float4 coalesced
  const float4* A4 = (const float4*)A;
  #pragma unroll
  for (int i = 0; i < 16; i++) {
    int idx = t + i * 256;            // 0..4095 float4s
    int r = idx >> 5, c4 = (idx & 31) << 2;
    int grow = rowbase + r;
    float4 v = make_float4(0.f, 0.f, 0.f, 0.f);
    if (grow < n) v = A4[(size_t)grow * 32 + (idx & 31)];
    short4 s;
    s.x = (short)f2bf(v.x); s.y = (short)f2bf(v.y);
    s.z = (short)f2bf(v.z); s.w = (short)f2bf(v.w);
    *(short4*)&As[r * LDA + c4] = s;
  }
  __syncthreads();

  int wv = t >> 6;              // wave 0..3
  int lane = t & 63;
  int lrow = lane & 15;
  int lk = (lane >> 4) << 3;    // k-offset 0,8,16,24
  int wr0 = wv * 32;            // wave's first row within tile

  // hoist all A fragments (2 m-tiles x 4 k-chunks) into registers
  const short* base0 = &As[(wr0 + lrow) * LDA + lk];
  const short* base1 = &As[(wr0 + 16 + lrow) * LDA + lk];
  bf16x8 a00 = *(const bf16x8*)(base0 + 0);
  bf16x8 a01 = *(const bf16x8*)(base0 + 32);
  bf16x8 a02 = *(const bf16x8*)(base0 + 64);
  bf16x8 a03 = *(const bf16x8*)(base0 + 96);
  bf16x8 a10 = *(const bf16x8*)(base1 + 0);
  bf16x8 a11 = *(const bf16x8*)(base1 + 32);
  bf16x8 a12 = *(const bf16x8*)(base1 + 64);
  bf16x8 a13 = *(const bf16x8*)(base1 + 96);

  // dinv for the 8 output rows this lane owns
  int r0 = rowbase + wr0 + ((lane >> 4) << 2);
  float dv0[4], dv1[4];
  #pragma unroll
  for (int r = 0; r < 4; r++) {
    int g0 = r0 + r, g1 = r0 + 16 + r;
    dv0[r] = (g0 < n) ? dinv[g0] : 0.f;
    dv1[r] = (g1 < n) ? dinv[g1] : 0.f;
  }

  #pragma unroll
  for (int nt = 0; nt < 8; nt++) {
    const short* bb = &Ws[(nt * 16 + lrow) * LDA + lk];
    f32x4 acc0 = {0.f, 0.f, 0.f, 0.f};
    f32x4 acc1 = {0.f, 0.f, 0.f, 0.f};
    bf16x8 b0 = *(const bf16x8*)(bb + 0);
    acc0 = __builtin_amdgcn_mfma_f32_16x16x32_bf16(a00, b0, acc0, 0, 0, 0);
    acc1 = __builtin_amdgcn_mfma_f32_16x16x32_bf16(a10, b0, acc1, 0, 0, 0);
    bf16x8 b1 = *(const bf16x8*)(bb + 32);
    acc0 = __builtin_amdgcn_mfma_f32_16x16x32_bf16(a01, b1, acc0, 0, 0, 0);
    acc1 = __builtin_amdgcn_mfma_f32_16x16x32_bf16(a11, b1, acc1, 0, 0, 0);
    bf16x8 b2 = *(const bf16x8*)(bb + 64);
    acc0 = __builtin_amdgcn_mfma_f32_16x16x32_bf16(a02, b2, acc0, 0, 0, 0);
    acc1 = __builtin_amdgcn_mfma_f32_16x16x32_bf16(a12, b2, acc1, 0, 0, 0);
    bf16x8 b3 = *(const bf16x8*)(bb + 96);
    acc0 = __builtin_amdgcn_mfma_f32_16x16x32_bf16(a03, b3, acc0, 0, 0, 0);
    acc1 = __builtin_amdgcn_mfma_f32_16x16x32_bf16(a13, b3, acc1, 0, 0, 0);
    #pragma unroll
    for (int r = 0; r < 4; r++) {
      int g0 = r0 + r;
      if (g0 < n) Out[(size_t)g0 * HDIM + nt * 16 + lrow] = f2bf(acc0[r] * dv0[r]);
      int g1 = r0 + 16 + r;
      if (g1 < n) Out[(size_t)g1 * HDIM + nt * 16 + lrow] = f2bf(acc1[r] * dv1[r]);
    }
  }
}

// ---------------- aggregation: one wave per dst node (bf16 T', fp32 accumulate) -------
template <int MODE>
__global__ __launch_bounds__(256) void agg_k(const unsigned short* __restrict__ T,
                                             const int* __restrict__ rowptr,
                                             const int* __restrict__ colx,
                                             const float* __restrict__ dinv,
                                             const float* __restrict__ bias,
                                             const float* __restrict__ lng,
                                             const float* __restrict__ lnb,
                                             float* __restrict__ Out, int n) {
  int wid = (blockIdx.x * 256 + threadIdx.x) >> 6;
  int lane = threadIdx.x & 63;
  if (wid >= n) return;
  int i = wid;
  float di = dinv[i];
  const unsigned int* T32 = (const unsigned int*)T;
  unsigned int us = T32[(size_t)i * 64 + lane];
  float a0x = bf_lo(us), a0y = bf_hi(us);
  float a1x = 0.f, a1y = 0.f;
  int beg = rowptr[i], end = rowptr[i + 1];
  int e = beg;
  int c0 = 0, c1 = 0;
  if (e < end) c0 = colx[e];
  if (e + 1 < end) c1 = colx[e + 1];
  for (; e + 1 < end; e += 2) {
    unsigned int u0 = T32[(size_t)c0 * 64 + lane];
    unsigned int u1 = T32[(size_t)c1 * 64 + lane];
    if (e + 2 < end) c0 = colx[e + 2];
    if (e + 3 < end) c1 = colx[e + 3];
    a0x += bf_lo(u0); a0y += bf_hi(u0);
    a1x += bf_lo(u1); a1y += bf_hi(u1);
  }
  if (e < end) {
    unsigned int u0 = T32[(size_t)c0 * 64 + lane];
    a0x += bf_lo(u0); a0y += bf_hi(u0);
  }
  float2 bb = ((const float2*)bias)[lane];
  float2 acc;
  acc.x = (a0x + a1x) * di + bb.x;
  acc.y = (a0y + a1y) * di + bb.y;
  if (MODE == 0) {
    acc.x = fmaxf(acc.x, 0.f);
    acc.y = fmaxf(acc.y, 0.f);
    float s1 = acc.x + acc.y;
    float s2 = acc.x * acc.x + acc.y * acc.y;
    for (int off = 1; off < 64; off <<= 1) {
      s1 += __shfl_xor(s1, off);
      s2 += __shfl_xor(s2, off);
    }
    float mu = s1 * (1.f / 128.f);
    float var = s2 * (1.f / 128.f) - mu * mu;
    float r = rsqrtf(var + EPSLN);
    float2 gg = ((const float2*)lng)[lane];
    float2 b2 = ((const float2*)lnb)[lane];
    acc.x = (acc.x - mu) * r * gg.x + b2.x;
    acc.y = (acc.y - mu) * r * gg.y + b2.y;
  }
  ((float2*)(Out + (size_t)i * HDIM))[lane] = acc;
}

// ---------------- fused head: relu -> Linear(128) -> Linear(2) -> log_softmax ---------
__global__ __launch_bounds__(256) void head_k(const float* __restrict__ emb,
                                              const float* __restrict__ W1_,
                                              const float* __restrict__ b1_,
                                              const float* __restrict__ W2_,
                                              const float* __restrict__ b2_,
                                              float* __restrict__ outp, int n) {
  __shared__ float hs[64 * HDIM];
  int t = threadIdx.x;
  int rowbase = blockIdx.x * 64;
  const float4* A4 = (const float4*)(emb + (size_t)rowbase * HDIM);
  for (int i = 0; i < 8; i++) {
    int fi = t + i * 256;
    int row = rowbase + (fi >> 5);
    float4 v = make_float4(0.f, 0.f, 0.f, 0.f);
    if (row < n) v = A4[fi];
    v.x = fmaxf(v.x, 0.f);
    v.y = fmaxf(v.y, 0.f);
    v.z = fmaxf(v.z, 0.f);
    v.w = fmaxf(v.w, 0.f);
    ((float4*)hs)[fi] = v;
  }
  __syncthreads();

  int tc = t & 31;
  int tr = t >> 5;
  float acc[8][4];
  float4 binit = ((const float4*)b1_)[tc];
  for (int i = 0; i < 8; i++) {
    acc[i][0] = binit.x; acc[i][1] = binit.y; acc[i][2] = binit.z; acc[i][3] = binit.w;
  }

  const float4* W4 = (const float4*)W1_;
  for (int k = 0; k < HDIM; k += 4) {
    float4 w0 = W4[(k + 0) * 32 + tc];
    float4 w1 = W4[(k + 1) * 32 + tc];
    float4 w2 = W4[(k + 2) * 32 + tc];
    float4 w3 = W4[(k + 3) * 32 + tc];
    for (int i = 0; i < 8; i++) {
      float4 h4 = *((const float4*)&hs[(tr * 8 + i) * HDIM + k]);
      acc[i][0] += h4.x * w0.x + h4.y * w1.x + h4.z * w2.x + h4.w * w3.x;
      acc[i][1] += h4.x * w0.y + h4.y * w1.y + h4.z * w2.y + h4.w * w3.y;
      acc[i][2] += h4.x * w0.z + h4.y * w1.z + h4.z * w2.z + h4.w * w3.z;
      acc[i][3] += h4.x * w0.w + h4.y * w1.w + h4.z * w2.w + h4.w * w3.w;
    }
  }

  float2 w2c[4];
  for (int j = 0; j < 4; j++) w2c[j] = ((const float2*)W2_)[4 * tc + j];
  float o0[8], o1[8];
  for (int i = 0; i < 8; i++) {
    o0[i] = acc[i][0] * w2c[0].x + acc[i][1] * w2c[1].x + acc[i][2] * w2c[2].x + acc[i][3] * w2c[3].x;
    o1[i] = acc[i][0] * w2c[0].y + acc[i][1] * w2c[1].y + acc[i][2] * w2c[2].y + acc[i][3] * w2c[3].y;
  }
  for (int off = 1; off < 32; off <<= 1) {
    for (int i = 0; i < 8; i++) {
      o0[i] += __shfl_xor(o0[i], off);
      o1[i] += __shfl_xor(o1[i], off);
    }
  }
  if (tc == 0) {
    float B0 = b2_[0], B1 = b2_[1];
    for (int i = 0; i < 8; i++) {
      int row = rowbase + tr * 8 + i;
      if (row < n) {
        float a = o0[i] + B0, b = o1[i] + B1;
        float m = fmaxf(a, b);
        float lse = m + logf(expf(a - m) + expf(b - m));
        outp[(size_t)row * 2 + 0] = a - lse;
        outp[(size_t)row * 2 + 1] = b - lse;
      }
    }
  }
}

// ---------------- launcher ----------------

extern "C" void kernel_launch(void* const* d_in, const int* in_sizes, int n_in,
                              void* d_out, int out_size, void* d_ws, size_t ws_size,
                              hipStream_t stream) {
  const float* x = (const float*)d_in[0];
  const int* ei = (const int*)d_in[1];
  const float* W1 = (const float*)d_in[2];
  const float* b1 = (const float*)d_in[3];
  const float* W2 = (const float*)d_in[4];
  const float* b2 = (const float*)d_in[5];
  const float* W3 = (const float*)d_in[6];
  const float* b3 = (const float*)d_in[7];
  const float* ln1g = (const float*)d_in[8];
  const float* ln1b = (const float*)d_in[9];
  const float* ln2g = (const float*)d_in[10];
  const float* ln2b = (const float*)d_in[11];
  const float* mpW1 = (const float*)d_in[12];
  const float* mpb1 = (const float*)d_in[13];
  const float* mpW2 = (const float*)d_in[14];
  const float* mpb2 = (const float*)d_in[15];

  const int N = in_sizes[0] / HDIM;
  const int E = in_sizes[1] / 2;
  const int* srcp = ei;
  const int* dstp = ei + E;
  const int NB = (N + 255) >> BSH;   // buckets of 256 nodes (<= 512)

  // carve workspace
  char* p = (char*)d_ws;
  auto carve = [&](size_t bytes) {
    void* r = (void*)p;
    p += (bytes + 255) & ~(size_t)255;
    return r;
  };
  int* bsize = (int*)carve(512 * 4);
  int* bbase = (int*)carve(513 * 4);
  int* bcur = (int*)carve(512 * 4);
  int* rowptr = (int*)carve((size_t)(N + 1) * 4);
  float* dinv = (float*)carve((size_t)N * 4);
  int* colx = (int*)carve((size_t)E * 4);
  uint2* binned = (uint2*)carve((size_t)E * 8);
  unsigned short* bufT = (unsigned short*)carve((size_t)N * HDIM * 2);  // bf16 T'
  float* bufAct = (float*)carve((size_t)N * HDIM * 4);                  // fp32 activations

  float* emb = (float*)d_out;                        // N x 128
  float* logits = (float*)d_out + (size_t)N * HDIM;  // N x 2

  const int chunkG = (E + CHUNK - 1) / CHUNK;

  hipMemsetAsync(bsize, 0, 512 * 4, stream);
  histA_k<<<chunkG, 256, 0, stream>>>(dstp, bsize, E);
  scanA_k<<<1, 256, 0, stream>>>(bsize, bbase, bcur, rowptr, NB, N, E);
  scatA_k<<<chunkG, 256, 0, stream>>>(srcp, dstp, bcur, binned, E);
  passB_k<<<NB, 256, 0, stream>>>(binned, bbase, rowptr, dinv, colx, N);

  const int gemmG = (N + 127) / 128;   // MFMA gemm: 128-row tiles
  const int headG = (N + 63) / 64;     // head: 64-row tiles
  const int aggG = (N * 64 + 255) / 256;

  // layer 1: x -> bufT (bf16, pre-scaled) -> (agg+relu+LN) bufAct
  gemm_k<<<gemmG, 256, 0, stream>>>(x, W1, dinv, bufT, N);
  agg_k<0><<<aggG, 256, 0, stream>>>(bufT, rowptr, colx, dinv, b1, ln1g, ln1b, bufAct, N);
  // layer 2
  gemm_k<<<gemmG, 256, 0, stream>>>(bufAct, W2, dinv, bufT, N);
  agg_k<0><<<aggG, 256, 0, stream>>>(bufT, rowptr, colx, dinv, b2, ln2g, ln2b, bufAct, N);
  // layer 3 -> emb (pre-relu) straight into d_out
  gemm_k<<<gemmG, 256, 0, stream>>>(bufAct, W3, dinv, bufT, N);
  agg_k<1><<<aggG, 256, 0, stream>>>(bufT, rowptr, colx, dinv, b3, nullptr, nullptr, emb, N);
  // head (fp32 register-blocked, fused log-softmax) — unchanged this round
  head_k<<<headG, 256, 0, stream>>>(emb, mpW1, mpb1, mpW2, mpb2, logits, N);
}

// Round 15
// 569.420 us; speedup vs baseline: 1.4396x; 1.0912x over previous
//
#include <hip/hip_runtime.h>
#include <math.h>

#define HDIM 128
#define EPSLN 1e-5f
#define BSH 8         // bucket shift: 256 nodes per bucket
#define CHUNK 8192    // edges per block in histA/scatA
#define EPB 32        // CHUNK/256
#define CAPB 8192     // LDS staging capacity (edges) per bucket in passB
#define LDA 136       // padded LDS row stride in shorts (272 B: 16B-aligned, 2-way banks)

typedef __attribute__((ext_vector_type(8))) short bf16x8;  // 8 bf16 (4 VGPRs)
typedef __attribute__((ext_vector_type(4))) float f32x4;   // MFMA accumulator

// bf16 helpers: RNE float->bf16, exact bf16->float via bit ops
__device__ __forceinline__ unsigned short f2bf(float f) {
  unsigned int u = __float_as_uint(f);
  u = u + 0x7fffu + ((u >> 16) & 1u);
  return (unsigned short)(u >> 16);
}
__device__ __forceinline__ float bf_lo(unsigned int packed) {
  return __uint_as_float(packed << 16);
}
__device__ __forceinline__ float bf_hi(unsigned int packed) {
  return __uint_as_float(packed & 0xffff0000u);
}

// ---------------- CSR build via bucket partition (no scattered 4B writes) ----------

__global__ __launch_bounds__(256) void histA_k(const int* __restrict__ dst,
                                               int* __restrict__ bsize, int E_) {
  __shared__ int h[512];
  int t = threadIdx.x;
  h[t] = 0; h[t + 256] = 0;
  __syncthreads();
  int base = blockIdx.x * CHUNK;
  for (int i = 0; i < EPB; i++) {
    int idx = base + i * 256 + t;
    if (idx < E_) atomicAdd(&h[dst[idx] >> BSH], 1);
  }
  __syncthreads();
  int v = h[t];       if (v) atomicAdd(&bsize[t], v);
  v = h[t + 256];     if (v) atomicAdd(&bsize[t + 256], v);
}

__global__ __launch_bounds__(256) void scanA_k(const int* __restrict__ bsize,
                                               int* __restrict__ bbase,
                                               int* __restrict__ bcur,
                                               int* __restrict__ rowptr,
                                               int NB, int n, int E_) {
  __shared__ int sm[512];
  int t = threadIdx.x;
  sm[t] = (t < NB) ? bsize[t] : 0;
  sm[t + 256] = (t + 256 < NB) ? bsize[t + 256] : 0;
  __syncthreads();
  for (int off = 1; off < 512; off <<= 1) {
    int v0 = (t >= off) ? sm[t - off] : 0;
    int v1 = (t + 256 >= off) ? sm[t + 256 - off] : 0;
    __syncthreads();
    sm[t] += v0;
    sm[t + 256] += v1;
    __syncthreads();
  }
  if (t < NB) { int ex = (t == 0) ? 0 : sm[t - 1]; bbase[t] = ex; bcur[t] = ex; }
  int u = t + 256;
  if (u < NB) { int ex = sm[u - 1]; bbase[u] = ex; bcur[u] = ex; }
  if (t == 0) { bbase[NB] = sm[NB - 1]; rowptr[n] = E_; }
}

__global__ __launch_bounds__(256) void scatA_k(const int* __restrict__ src,
                                               const int* __restrict__ dst,
                                               int* __restrict__ bcur,
                                               uint2* __restrict__ binned, int E_) {
  __shared__ int h[512];
  __shared__ int cur[512];
  int t = threadIdx.x;
  h[t] = 0; h[t + 256] = 0;
  __syncthreads();
  int base = blockIdx.x * CHUNK;
  for (int i = 0; i < EPB; i++) {
    int idx = base + i * 256 + t;
    if (idx < E_) atomicAdd(&h[dst[idx] >> BSH], 1);
  }
  __syncthreads();
  int v = h[t];       cur[t] = v ? atomicAdd(&bcur[t], v) : 0;
  v = h[t + 256];     cur[t + 256] = v ? atomicAdd(&bcur[t + 256], v) : 0;
  __syncthreads();
  for (int i = 0; i < EPB; i++) {
    int idx = base + i * 256 + t;
    if (idx < E_) {
      int d = dst[idx];
      int slot = atomicAdd(&cur[d >> BSH], 1);
      binned[slot] = make_uint2((unsigned)src[idx], (unsigned)d);
    }
  }
}

__global__ __launch_bounds__(256) void passB_k(const uint2* __restrict__ binned,
                                               const int* __restrict__ bbase,
                                               int* __restrict__ rowptr,
                                               float* __restrict__ dinv,
                                               int* __restrict__ colx, int n) {
  __shared__ int cnt[256];
  __shared__ int cur[256];
  __shared__ int stage[CAPB];
  int b = blockIdx.x;
  int t = threadIdx.x;
  int beg = bbase[b], end = bbase[b + 1];
  int sz = end - beg;
  int nb0 = b << BSH;
  cnt[t] = 0;
  __syncthreads();
  for (int i = t; i < sz; i += 256) {
    uint2 e = binned[beg + i];
    atomicAdd(&cnt[e.y & 255], 1);
  }
  __syncthreads();
  int myc = cnt[t];
  cur[t] = myc;
  __syncthreads();
  for (int off = 1; off < 256; off <<= 1) {
    int v = (t >= off) ? cur[t - off] : 0;
    __syncthreads();
    cur[t] += v;
    __syncthreads();
  }
  int excl = cur[t] - myc;
  int node = nb0 + t;
  if (node < n) {
    rowptr[node] = beg + excl;
    dinv[node] = rsqrtf((float)(myc + 1));  // +1 = self loop
  }
  __syncthreads();
  cur[t] = excl;
  __syncthreads();
  if (sz <= CAPB) {
    for (int i = t; i < sz; i += 256) {
      uint2 e = binned[beg + i];
      int slot = atomicAdd(&cur[e.y & 255], 1);
      stage[slot] = (int)e.x;
    }
    __syncthreads();
    for (int i = t; i < sz; i += 256) colx[beg + i] = stage[i];
  } else {
    for (int i = t; i < sz; i += 256) {
      uint2 e = binned[beg + i];
      int slot = atomicAdd(&cur[e.y & 255], 1);
      colx[beg + slot] = (int)e.x;
    }
  }
}

// ---------------- MFMA GEMM: T'[n x 128](bf16) = dinv ⊙ (bf16(A) @ bf16(W)) ----------
__global__ __launch_bounds__(256) void gemm_k(const float* __restrict__ A,
                                              const float* __restrict__ W,
                                              const float* __restrict__ dinv,
                                              unsigned short* __restrict__ Out, int n) {
  __shared__ short As[128 * LDA];
  __shared__ short Ws[128 * LDA];
  int t = threadIdx.x;
  int rowbase = blockIdx.x * 128;

  #pragma unroll
  for (int i = 0; i < 64; i++) {
    int idx = t + i * 256;            // 0..16383
    int k = idx >> 7, c = idx & 127;
    Ws[c * LDA + k] = (short)f2bf(W[idx]);
  }
  const float4* A4 = (const float4*)A;
  #pragma unroll
  for (int i = 0; i < 16; i++) {
    int idx = t + i * 256;            // 0..4095 float4s
    int r = idx >> 5, c4 = (idx & 31) << 2;
    int grow = rowbase + r;
    float4 v = make_float4(0.f, 0.f, 0.f, 0.f);
    if (grow < n) v = A4[(size_t)grow * 32 + (idx & 31)];
    short4 s;
    s.x = (short)f2bf(v.x); s.y = (short)f2bf(v.y);
    s.z = (short)f2bf(v.z); s.w = (short)f2bf(v.w);
    *(short4*)&As[r * LDA + c4] = s;
  }
  __syncthreads();

  int wv = t >> 6;
  int lane = t & 63;
  int lrow = lane & 15;
  int lk = (lane >> 4) << 3;
  int wr0 = wv * 32;

  const short* base0 = &As[(wr0 + lrow) * LDA + lk];
  const short* base1 = &As[(wr0 + 16 + lrow) * LDA + lk];
  bf16x8 a00 = *(const bf16x8*)(base0 + 0);
  bf16x8 a01 = *(const bf16x8*)(base0 + 32);
  bf16x8 a02 = *(const bf16x8*)(base0 + 64);
  bf16x8 a03 = *(const bf16x8*)(base0 + 96);
  bf16x8 a10 = *(const bf16x8*)(base1 + 0);
  bf16x8 a11 = *(const bf16x8*)(base1 + 32);
  bf16x8 a12 = *(const bf16x8*)(base1 + 64);
  bf16x8 a13 = *(const bf16x8*)(base1 + 96);

  int r0 = rowbase + wr0 + ((lane >> 4) << 2);
  float dv0[4], dv1[4];
  #pragma unroll
  for (int r = 0; r < 4; r++) {
    int g0 = r0 + r, g1 = r0 + 16 + r;
    dv0[r] = (g0 < n) ? dinv[g0] : 0.f;
    dv1[r] = (g1 < n) ? dinv[g1] : 0.f;
  }

  #pragma unroll
  for (int nt = 0; nt < 8; nt++) {
    const short* bb = &Ws[(nt * 16 + lrow) * LDA + lk];
    f32x4 acc0 = {0.f, 0.f, 0.f, 0.f};
    f32x4 acc1 = {0.f, 0.f, 0.f, 0.f};
    bf16x8 b0 = *(const bf16x8*)(bb + 0);
    acc0 = __builtin_amdgcn_mfma_f32_16x16x32_bf16(a00, b0, acc0, 0, 0, 0);
    acc1 = __builtin_amdgcn_mfma_f32_16x16x32_bf16(a10, b0, acc1, 0, 0, 0);
    bf16x8 b1 = *(const bf16x8*)(bb + 32);
    acc0 = __builtin_amdgcn_mfma_f32_16x16x32_bf16(a01, b1, acc0, 0, 0, 0);
    acc1 = __builtin_amdgcn_mfma_f32_16x16x32_bf16(a11, b1, acc1, 0, 0, 0);
    bf16x8 b2 = *(const bf16x8*)(bb + 64);
    acc0 = __builtin_amdgcn_mfma_f32_16x16x32_bf16(a02, b2, acc0, 0, 0, 0);
    acc1 = __builtin_amdgcn_mfma_f32_16x16x32_bf16(a12, b2, acc1, 0, 0, 0);
    bf16x8 b3 = *(const bf16x8*)(bb + 96);
    acc0 = __builtin_amdgcn_mfma_f32_16x16x32_bf16(a03, b3, acc0, 0, 0, 0);
    acc1 = __builtin_amdgcn_mfma_f32_16x16x32_bf16(a13, b3, acc1, 0, 0, 0);
    #pragma unroll
    for (int r = 0; r < 4; r++) {
      int g0 = r0 + r;
      if (g0 < n) Out[(size_t)g0 * HDIM + nt * 16 + lrow] = f2bf(acc0[r] * dv0[r]);
      int g1 = r0 + 16 + r;
      if (g1 < n) Out[(size_t)g1 * HDIM + nt * 16 + lrow] = f2bf(acc1[r] * dv1[r]);
    }
  }
}

// ---------------- aggregation: one wave per dst node (bf16 T', fp32 accumulate) -------
template <int MODE>
__global__ __launch_bounds__(256) void agg_k(const unsigned short* __restrict__ T,
                                             const int* __restrict__ rowptr,
                                             const int* __restrict__ colx,
                                             const float* __restrict__ dinv,
                                             const float* __restrict__ bias,
                                             const float* __restrict__ lng,
                                             const float* __restrict__ lnb,
                                             float* __restrict__ Out, int n) {
  int wid = (blockIdx.x * 256 + threadIdx.x) >> 6;
  int lane = threadIdx.x & 63;
  if (wid >= n) return;
  int i = wid;
  float di = dinv[i];
  const unsigned int* T32 = (const unsigned int*)T;
  unsigned int us = T32[(size_t)i * 64 + lane];
  float a0x = bf_lo(us), a0y = bf_hi(us);
  float a1x = 0.f, a1y = 0.f;
  int beg = rowptr[i], end = rowptr[i + 1];
  int e = beg;
  int c0 = 0, c1 = 0;
  if (e < end) c0 = colx[e];
  if (e + 1 < end) c1 = colx[e + 1];
  for (; e + 1 < end; e += 2) {
    unsigned int u0 = T32[(size_t)c0 * 64 + lane];
    unsigned int u1 = T32[(size_t)c1 * 64 + lane];
    if (e + 2 < end) c0 = colx[e + 2];
    if (e + 3 < end) c1 = colx[e + 3];
    a0x += bf_lo(u0); a0y += bf_hi(u0);
    a1x += bf_lo(u1); a1y += bf_hi(u1);
  }
  if (e < end) {
    unsigned int u0 = T32[(size_t)c0 * 64 + lane];
    a0x += bf_lo(u0); a0y += bf_hi(u0);
  }
  float2 bb = ((const float2*)bias)[lane];
  float2 acc;
  acc.x = (a0x + a1x) * di + bb.x;
  acc.y = (a0y + a1y) * di + bb.y;
  if (MODE == 0) {
    acc.x = fmaxf(acc.x, 0.f);
    acc.y = fmaxf(acc.y, 0.f);
    float s1 = acc.x + acc.y;
    float s2 = acc.x * acc.x + acc.y * acc.y;
    for (int off = 1; off < 64; off <<= 1) {
      s1 += __shfl_xor(s1, off);
      s2 += __shfl_xor(s2, off);
    }
    float mu = s1 * (1.f / 128.f);
    float var = s2 * (1.f / 128.f) - mu * mu;
    float r = rsqrtf(var + EPSLN);
    float2 gg = ((const float2*)lng)[lane];
    float2 b2 = ((const float2*)lnb)[lane];
    acc.x = (acc.x - mu) * r * gg.x + b2.x;
    acc.y = (acc.y - mu) * r * gg.y + b2.y;
  }
  ((float2*)(Out + (size_t)i * HDIM))[lane] = acc;
}

// ---------------- MFMA head: relu -> Linear(128) -> Linear(2) -> log_softmax ----------
// Same tile structure as gemm_k.  Second linear + log-softmax fused in epilogue:
// lane owns col nt*16+lrow of z per n-tile; 16-lane shfl_xor completes the 128-dot.
__global__ __launch_bounds__(256) void head_k(const float* __restrict__ emb,
                                              const float* __restrict__ W1_,
                                              const float* __restrict__ b1_,
                                              const float* __restrict__ W2_,
                                              const float* __restrict__ b2_,
                                              float* __restrict__ outp, int n) {
  __shared__ short As[128 * LDA];
  __shared__ short Ws[128 * LDA];
  int t = threadIdx.x;
  int rowbase = blockIdx.x * 128;

  #pragma unroll
  for (int i = 0; i < 64; i++) {
    int idx = t + i * 256;
    int k = idx >> 7, c = idx & 127;
    Ws[c * LDA + k] = (short)f2bf(W1_[idx]);
  }
  const float4* A4 = (const float4*)emb;
  #pragma unroll
  for (int i = 0; i < 16; i++) {
    int idx = t + i * 256;
    int r = idx >> 5, c4 = (idx & 31) << 2;
    int grow = rowbase + r;
    float4 v = make_float4(0.f, 0.f, 0.f, 0.f);
    if (grow < n) v = A4[(size_t)grow * 32 + (idx & 31)];
    short4 s;
    s.x = (short)f2bf(fmaxf(v.x, 0.f)); s.y = (short)f2bf(fmaxf(v.y, 0.f));
    s.z = (short)f2bf(fmaxf(v.z, 0.f)); s.w = (short)f2bf(fmaxf(v.w, 0.f));
    *(short4*)&As[r * LDA + c4] = s;
  }
  __syncthreads();

  int wv = t >> 6;
  int lane = t & 63;
  int lrow = lane & 15;
  int lk = (lane >> 4) << 3;
  int wr0 = wv * 32;

  const short* base0 = &As[(wr0 + lrow) * LDA + lk];
  const short* base1 = &As[(wr0 + 16 + lrow) * LDA + lk];
  bf16x8 a00 = *(const bf16x8*)(base0 + 0);
  bf16x8 a01 = *(const bf16x8*)(base0 + 32);
  bf16x8 a02 = *(const bf16x8*)(base0 + 64);
  bf16x8 a03 = *(const bf16x8*)(base0 + 96);
  bf16x8 a10 = *(const bf16x8*)(base1 + 0);
  bf16x8 a11 = *(const bf16x8*)(base1 + 32);
  bf16x8 a12 = *(const bf16x8*)(base1 + 64);
  bf16x8 a13 = *(const bf16x8*)(base1 + 96);

  float o0m0[4] = {0.f, 0.f, 0.f, 0.f}, o1m0[4] = {0.f, 0.f, 0.f, 0.f};
  float o0m1[4] = {0.f, 0.f, 0.f, 0.f}, o1m1[4] = {0.f, 0.f, 0.f, 0.f};

  #pragma unroll
  for (int nt = 0; nt < 8; nt++) {
    int col = nt * 16 + lrow;
    const short* bb = &Ws[col * LDA + lk];
    f32x4 acc0 = {0.f, 0.f, 0.f, 0.f};
    f32x4 acc1 = {0.f, 0.f, 0.f, 0.f};
    bf16x8 b0 = *(const bf16x8*)(bb + 0);
    acc0 = __builtin_amdgcn_mfma_f32_16x16x32_bf16(a00, b0, acc0, 0, 0, 0);
    acc1 = __builtin_amdgcn_mfma_f32_16x16x32_bf16(a10, b0, acc1, 0, 0, 0);
    bf16x8 b1 = *(const bf16x8*)(bb + 32);
    acc0 = __builtin_amdgcn_mfma_f32_16x16x32_bf16(a01, b1, acc0, 0, 0, 0);
    acc1 = __builtin_amdgcn_mfma_f32_16x16x32_bf16(a11, b1, acc1, 0, 0, 0);
    bf16x8 b2 = *(const bf16x8*)(bb + 64);
    acc0 = __builtin_amdgcn_mfma_f32_16x16x32_bf16(a02, b2, acc0, 0, 0, 0);
    acc1 = __builtin_amdgcn_mfma_f32_16x16x32_bf16(a12, b2, acc1, 0, 0, 0);
    bf16x8 b3 = *(const bf16x8*)(bb + 96);
    acc0 = __builtin_amdgcn_mfma_f32_16x16x32_bf16(a03, b3, acc0, 0, 0, 0);
    acc1 = __builtin_amdgcn_mfma_f32_16x16x32_bf16(a13, b3, acc1, 0, 0, 0);
    // z = acc + b1[col]; partial logits o += z * W2[col][cls]
    float bv = b1_[col];
    float w20 = W2_[col * 2 + 0], w21 = W2_[col * 2 + 1];
    #pragma unroll
    for (int r = 0; r < 4; r++) {
      float z0 = acc0[r] + bv;
      float z1 = acc1[r] + bv;
      o0m0[r] += z0 * w20;  o1m0[r] += z0 * w21;
      o0m1[r] += z1 * w20;  o1m1[r] += z1 * w21;
    }
  }
  // reduce across the 16 lanes (lrow 0..15) sharing each row group
  #pragma unroll
  for (int off = 1; off < 16; off <<= 1) {
    #pragma unroll
    for (int r = 0; r < 4; r++) {
      o0m0[r] += __shfl_xor(o0m0[r], off);
      o1m0[r] += __shfl_xor(o1m0[r], off);
      o0m1[r] += __shfl_xor(o0m1[r], off);
      o1m1[r] += __shfl_xor(o1m1[r], off);
    }
  }
  if (lrow == 0) {
    float B0 = b2_[0], B1 = b2_[1];
    int r0 = rowbase + wr0 + ((lane >> 4) << 2);
    #pragma unroll
    for (int r = 0; r < 4; r++) {
      int g0 = r0 + r;
      if (g0 < n) {
        float a = o0m0[r] + B0, b = o1m0[r] + B1;
        float m = fmaxf(a, b);
        float lse = m + logf(expf(a - m) + expf(b - m));
        outp[(size_t)g0 * 2 + 0] = a - lse;
        outp[(size_t)g0 * 2 + 1] = b - lse;
      }
      int g1 = r0 + 16 + r;
      if (g1 < n) {
        float a = o0m1[r] + B0, b = o1m1[r] + B1;
        float m = fmaxf(a, b);
        float lse = m + logf(expf(a - m) + expf(b - m));
        outp[(size_t)g1 * 2 + 0] = a - lse;
        outp[(size_t)g1 * 2 + 1] = b - lse;
      }
    }
  }
}

// ---------------- launcher ----------------

extern "C" void kernel_launch(void* const* d_in, const int* in_sizes, int n_in,
                              void* d_out, int out_size, void* d_ws, size_t ws_size,
                              hipStream_t stream) {
  const float* x = (const float*)d_in[0];
  const int* ei = (const int*)d_in[1];
  const float* W1 = (const float*)d_in[2];
  const float* b1 = (const float*)d_in[3];
  const float* W2 = (const float*)d_in[4];
  const float* b2 = (const float*)d_in[5];
  const float* W3 = (const float*)d_in[6];
  const float* b3 = (const float*)d_in[7];
  const float* ln1g = (const float*)d_in[8];
  const float* ln1b = (const float*)d_in[9];
  const float* ln2g = (const float*)d_in[10];
  const float* ln2b = (const float*)d_in[11];
  const float* mpW1 = (const float*)d_in[12];
  const float* mpb1 = (const float*)d_in[13];
  const float* mpW2 = (const float*)d_in[14];
  const float* mpb2 = (const float*)d_in[15];

  const int N = in_sizes[0] / HDIM;
  const int E = in_sizes[1] / 2;
  const int* srcp = ei;
  const int* dstp = ei + E;
  const int NB = (N + 255) >> BSH;

  char* p = (char*)d_ws;
  auto carve = [&](size_t bytes) {
    void* r = (void*)p;
    p += (bytes + 255) & ~(size_t)255;
    return r;
  };
  int* bsize = (int*)carve(512 * 4);
  int* bbase = (int*)carve(513 * 4);
  int* bcur = (int*)carve(512 * 4);
  int* rowptr = (int*)carve((size_t)(N + 1) * 4);
  float* dinv = (float*)carve((size_t)N * 4);
  int* colx = (int*)carve((size_t)E * 4);
  uint2* binned = (uint2*)carve((size_t)E * 8);
  unsigned short* bufT = (unsigned short*)carve((size_t)N * HDIM * 2);
  float* bufAct = (float*)carve((size_t)N * HDIM * 4);

  float* emb = (float*)d_out;
  float* logits = (float*)d_out + (size_t)N * HDIM;

  const int chunkG = (E + CHUNK - 1) / CHUNK;

  hipMemsetAsync(bsize, 0, 512 * 4, stream);
  histA_k<<<chunkG, 256, 0, stream>>>(dstp, bsize, E);
  scanA_k<<<1, 256, 0, stream>>>(bsize, bbase, bcur, rowptr, NB, N, E);
  scatA_k<<<chunkG, 256, 0, stream>>>(srcp, dstp, bcur, binned, E);
  passB_k<<<NB, 256, 0, stream>>>(binned, bbase, rowptr, dinv, colx, N);

  const int gemmG = (N + 127) / 128;
  const int aggG = (N * 64 + 255) / 256;

  gemm_k<<<gemmG, 256, 0, stream>>>(x, W1, dinv, bufT, N);
  agg_k<0><<<aggG, 256, 0, stream>>>(bufT, rowptr, colx, dinv, b1, ln1g, ln1b, bufAct, N);
  gemm_k<<<gemmG, 256, 0, stream>>>(bufAct, W2, dinv, bufT, N);
  agg_k<0><<<aggG, 256, 0, stream>>>(bufT, rowptr, colx, dinv, b2, ln2g, ln2b, bufAct, N);
  gemm_k<<<gemmG, 256, 0, stream>>>(bufAct, W3, dinv, bufT, N);
  agg_k<1><<<aggG, 256, 0, stream>>>(bufT, rowptr, colx, dinv, b3, nullptr, nullptr, emb, N);
  // head: MFMA, fused second-linear + log-softmax
  head_k<<<gemmG, 256, 0, stream>>>(emb, mpW1, mpb1, mpW2, mpb2, logits, N);
}